// Round 6
// baseline (261.468 us; speedup 1.0000x reference)
//
#include <hip/hip_runtime.h>
#include <stdint.h>

#define L_SEQ   2048
#define DM      1024
#define NH      16
#define DK      64
#define BATCH   4
#define M_TOK   (BATCH * L_SEQ)   // 8192

typedef __attribute__((ext_vector_type(8))) short bf16x8;
typedef __attribute__((ext_vector_type(4))) float f32x4;
typedef __attribute__((ext_vector_type(16))) float f32x16;
typedef __attribute__((ext_vector_type(4))) unsigned int u32x4;

typedef __attribute__((address_space(1))) void void_g;
typedef __attribute__((address_space(3))) void void_l;

#define EXP2F(x) __builtin_amdgcn_exp2f(x)

__device__ __forceinline__ unsigned short f2bf(float f) {
  unsigned int u = __builtin_bit_cast(unsigned int, f);
  u += 0x7FFFu + ((u >> 16) & 1u);
  return (unsigned short)(u >> 16);
}

// ---------------- fp32 -> bf16 converts ----------------
__global__ void cvt_f32_bf16(const float* __restrict__ src,
                             unsigned short* __restrict__ dst, int n4) {
  int i = blockIdx.x * blockDim.x + threadIdx.x;
  int stride = gridDim.x * blockDim.x;
  for (; i < n4; i += stride) {
    float4 v = ((const float4*)src)[i];
    ushort4 o;
    o.x = f2bf(v.x); o.y = f2bf(v.y); o.z = f2bf(v.z); o.w = f2bf(v.w);
    ((ushort4*)dst)[i] = o;
  }
}

// 4 weight matrices (1024x1024 each) -> contiguous bf16 dst, one launch
__global__ void cvt_w4(const float* __restrict__ s0, const float* __restrict__ s1,
                       const float* __restrict__ s2, const float* __restrict__ s3,
                       unsigned short* __restrict__ dst) {
  int i = blockIdx.x * blockDim.x + threadIdx.x;      // 0 .. 4*262144-1
  int sel = i >> 18, j = i & 0x3FFFF;
  const float* s = sel == 0 ? s0 : sel == 1 ? s1 : sel == 2 ? s2 : s3;
  float4 v = ((const float4*)s)[j];
  ushort4 o;
  o.x = f2bf(v.x); o.y = f2bf(v.y); o.z = f2bf(v.z); o.w = f2bf(v.w);
  ((ushort4*)(dst + (size_t)sel * DM * DM))[j] = o;
}

// ---------------- bf16 GEMM: C = (A @ B^T + bias) * scale ----------------
#define BM 128
#define BN 128
#define BKK 32

template <int EPI>
__global__ __launch_bounds__(256) void gemm_bt(
    const unsigned short* __restrict__ A,
    const unsigned short* __restrict__ Bw,
    const float* __restrict__ bias, float scale,
    void* __restrict__ out, int M, int N, int K) {
  __shared__ unsigned short As[BM * BKK];
  __shared__ unsigned short Bs[BN * BKK];

  const int tidx = threadIdx.x;
  const int wid = tidx >> 6, lane = tidx & 63;
  const int wm = wid >> 1, wn = wid & 1;
  const int tm = blockIdx.y * BM, tn = blockIdx.x * BN;
  const int lr = lane & 15;
  const int lk = (lane >> 4) * 8;

  f32x4 acc[4][4];
#pragma unroll
  for (int m = 0; m < 4; ++m)
#pragma unroll
    for (int n = 0; n < 4; ++n) acc[m][n] = (f32x4)0.0f;

  for (int k0 = 0; k0 < K; k0 += BKK) {
#pragma unroll
    for (int j = 0; j < 2; ++j) {
      int e0 = (wid * 2 + j) * 512;
      int e = e0 + lane * 8;
      int r = e >> 5, c = e & 31;
      __builtin_amdgcn_global_load_lds(
          (const void_g*)(A + (size_t)(tm + r) * K + k0 + c),
          (void_l*)(As + e0), 16, 0, 0);
      __builtin_amdgcn_global_load_lds(
          (const void_g*)(Bw + (size_t)(tn + r) * K + k0 + c),
          (void_l*)(Bs + e0), 16, 0, 0);
    }
    __syncthreads();

    bf16x8 a[4], b[4];
#pragma unroll
    for (int m = 0; m < 4; ++m)
      a[m] = *(const bf16x8*)&As[(wm * 64 + m * 16 + lr) * BKK + lk];
#pragma unroll
    for (int n = 0; n < 4; ++n)
      b[n] = *(const bf16x8*)&Bs[(wn * 64 + n * 16 + lr) * BKK + lk];
#pragma unroll
    for (int m = 0; m < 4; ++m)
#pragma unroll
      for (int n = 0; n < 4; ++n)
        acc[m][n] = __builtin_amdgcn_mfma_f32_16x16x32_bf16(a[m], b[n], acc[m][n], 0, 0, 0);
    __syncthreads();
  }

#pragma unroll
  for (int m = 0; m < 4; ++m) {
    int row0 = tm + wm * 64 + m * 16 + (lane >> 4) * 4;
#pragma unroll
    for (int n = 0; n < 4; ++n) {
      int col = tn + wn * 64 + n * 16 + (lane & 15);
      float bc = bias[col];
#pragma unroll
      for (int jj = 0; jj < 4; ++jj) {
        float v = (acc[m][n][jj] + bc) * scale;
        int R = row0 + jj;
        if (EPI == 2) {
          ((float*)out)[(size_t)R * DM + col] = v;
        } else {
          int bb = R >> 11, ll = R & (L_SEQ - 1);
          int h = col >> 6, dd = col & 63;
          if (EPI == 0)
            ((unsigned short*)out)[(((size_t)bb * NH + h) * L_SEQ + ll) * DK + dd] = f2bf(v);
          else
            ((unsigned short*)out)[(((size_t)bb * NH + h) * DK + dd) * L_SEQ + ll] = f2bf(v);
        }
      }
    }
  }
}

// ---------------- flash attention: swapped 32x32, 32 q/wave ----------------
// Q,K: [B,H,L,DK] bf16 (Q pre-scaled by 0.125*log2e). VT: [B,H,DK,L] bf16.
#define KVB 64
#define LDK 68                 // 34-dword rows -> <=2-way banks (free)
#define NTILE (L_SEQ / KVB)
#define CLIP2 144.269504f      // 100*log2(e)
#define THR2  11.5415f         // 8*log2(e)

__device__ __forceinline__ bf16x8 lds_frag(const unsigned short* p) {
  uint2 a = *(const uint2*)p;
  uint2 b = *(const uint2*)(p + 4);
  u32x4 t = {a.x, a.y, b.x, b.y};
  return __builtin_bit_cast(bf16x8, t);
}

__device__ __forceinline__ void lds_st16(unsigned short* p, uint4 v) {
  *(uint2*)p = make_uint2(v.x, v.y);
  *(uint2*)(p + 4) = make_uint2(v.z, v.w);
}

// D.lo16 = bf16(a), D.hi16 = bf16(b)   (order verified against round-3-proven
// perm-based pack: v_perm sel 0-3 selects from S1, so both are {lo:a, hi:b})
__device__ __forceinline__ unsigned cvtpk(float a, float b) {
  unsigned r;
  asm("v_cvt_pk_bf16_f32 %0, %1, %2" : "=v"(r) : "v"(a), "v"(b));
  return r;
}

// a' = {a.lo32lanes, b.lo32lanes}; b' = {a.hi32lanes, b.hi32lanes}
// Round-3-VERIFIED shfl implementation (permlane builtin/asm both failed:
// asm form is alias-hazardous, builtin return-pair order unverified).
__device__ __forceinline__ void pl32swap(unsigned& a, unsigned& b) {
  unsigned sa = (unsigned)__shfl_xor((int)a, 32);
  unsigned sb = (unsigned)__shfl_xor((int)b, 32);
  int hi = (threadIdx.x & 63) >> 5;
  unsigned na = hi ? sb : a;
  unsigned nb = hi ? b : sa;
  a = na; b = nb;
}

// every lane gets (x[lane&31], x[(lane&31)+32])
__device__ __forceinline__ void xpair32(float x, float& lo, float& hi2) {
  unsigned a = __builtin_bit_cast(unsigned, x), b = a;
  pl32swap(a, b);
  lo = __builtin_bit_cast(float, a);
  hi2 = __builtin_bit_cast(float, b);
}

#define MFMA32(a, b, c) __builtin_amdgcn_mfma_f32_32x32x16_bf16(a, b, c, 0, 0, 0)

__global__ __launch_bounds__(256, 4) void flash_attn(
    const unsigned short* __restrict__ Qg,
    const unsigned short* __restrict__ Kg,
    const unsigned short* __restrict__ VTg,
    unsigned short* __restrict__ ctx) {
  __shared__ unsigned short Ks[2][64 * LDK];
  __shared__ unsigned short Vs[2][64 * LDK];

  const int bh = blockIdx.x, b = bh >> 4, h = bh & 15;
  const int q0 = blockIdx.y * 128;
  const int tid = threadIdx.x;
  const int w = tid >> 6, lane = tid & 63;
  const int l31 = lane & 31, hi = lane >> 5;
  const size_t head = (size_t)bh * (L_SEQ * DK);

  const int srow = w * 16 + (lane >> 2);     // staging row (4 waves cover 64)
  const int scol = (lane & 3) * 16;

  // Q fragments (B-operand layout: col=lane&31, k=hi*8+j), 32 q rows/wave
  bf16x8 qf[4];
  {
    const unsigned short* qp = Qg + head + (size_t)(q0 + w * 32 + l31) * DK + hi * 8;
#pragma unroll
    for (int ks = 0; ks < 4; ++ks) qf[ks] = *(const bf16x8*)(qp + ks * 16);
  }

  f32x16 o[2];
  o[0] = (f32x16)0.0f; o[1] = (f32x16)0.0f;
  float mq = -1e30f, lq = 0.0f;

  { // prologue: stage tile 0 into buffer 0
    const unsigned short* kp = Kg + head + (size_t)srow * DK + scol;
    uint4 k0 = *(const uint4*)kp, k1 = *(const uint4*)(kp + 8);
    const unsigned short* vp = VTg + head + (size_t)srow * L_SEQ + scol;
    uint4 v0 = *(const uint4*)vp, v1 = *(const uint4*)(vp + 8);
    lds_st16(Ks[0] + srow * LDK + scol, k0);
    lds_st16(Ks[0] + srow * LDK + scol + 8, k1);
    lds_st16(Vs[0] + srow * LDK + scol, v0);
    lds_st16(Vs[0] + srow * LDK + scol + 8, v1);
  }
  __syncthreads();

  int cur = 0;
  for (int t = 0; t < NTILE; ++t) {
    uint4 kr0, kr1, vr0, vr1;
    const int kv0n = (t + 1) * KVB;
    // (a) issue next K loads early (HBM/L2 latency hides under QK+softmax)
    if (t + 1 < NTILE) {
      const unsigned short* kp = Kg + head + (size_t)(kv0n + srow) * DK + scol;
      kr0 = *(const uint4*)kp; kr1 = *(const uint4*)(kp + 8);
    }

    // (b) QK^T: S[kv][q], lane's q = l31
    f32x16 s0 = (f32x16)0.0f, s1 = (f32x16)0.0f;
#pragma unroll
    for (int ks = 0; ks < 4; ++ks) {
      bf16x8 k0 = lds_frag(Ks[cur] + l31 * LDK + ks * 16 + hi * 8);
      s0 = MFMA32(k0, qf[ks], s0);
      bf16x8 k1 = lds_frag(Ks[cur] + (32 + l31) * LDK + ks * 16 + hi * 8);
      s1 = MFMA32(k1, qf[ks], s1);
    }

    // (c) clip + tile max (med3 clamp)
    float tmax = -CLIP2;
#pragma unroll
    for (int r = 0; r < 16; ++r) {
      s0[r] = __builtin_amdgcn_fmed3f(s0[r], -CLIP2, CLIP2);
      s1[r] = __builtin_amdgcn_fmed3f(s1[r], -CLIP2, CLIP2);
      tmax = fmaxf(tmax, fmaxf(s0[r], s1[r]));
    }
    {
      float a, c; xpair32(tmax, a, c);
      tmax = fmaxf(a, c);
    }
    // defer-max (T13)
    if (!__all(tmax - mq <= THR2)) {
      float mn = fmaxf(mq, tmax);
      float corr = EXP2F(mq - mn);
      lq *= corr;
#pragma unroll
      for (int r = 0; r < 16; ++r) { o[0][r] *= corr; o[1][r] *= corr; }
      mq = mn;
    }
    float ls = 0.0f;
#pragma unroll
    for (int r = 0; r < 16; ++r) {
      s0[r] = EXP2F(s0[r] - mq); ls += s0[r];
      s1[r] = EXP2F(s1[r] - mq); ls += s1[r];
    }
    {
      float a, c; xpair32(ls, a, c);
      lq += a + c;
    }

    // (d) pack P into PV B-frags: frag[ks] elem j <- P[kv=16ks+8hi+j][q]
    bf16x8 pa[4];
#pragma unroll
    for (int ks = 0; ks < 4; ++ks) {
      const int s8 = (ks & 1) * 8;
      const f32x16 sv = (ks < 2) ? s0 : s1;
      unsigned uA0 = cvtpk(sv[s8 + 0], sv[s8 + 1]);
      unsigned uA1 = cvtpk(sv[s8 + 2], sv[s8 + 3]);
      unsigned uB0 = cvtpk(sv[s8 + 4], sv[s8 + 5]);
      unsigned uB1 = cvtpk(sv[s8 + 6], sv[s8 + 7]);
      pl32swap(uA0, uB0);
      pl32swap(uA1, uB1);
      u32x4 tt = {uA0, uA1, uB0, uB1};
      pa[ks] = __builtin_bit_cast(bf16x8, tt);
    }

    // (e) issue next V loads (hides under PV MFMAs)
    if (t + 1 < NTILE) {
      const unsigned short* vp = VTg + head + (size_t)srow * L_SEQ + kv0n + scol;
      vr0 = *(const uint4*)vp; vr1 = *(const uint4*)(vp + 8);
    }

    // (f) PV: O^T[d][q] += VT[d][kv] * P^T[q][kv]
#pragma unroll
    for (int jb = 0; jb < 2; ++jb)
#pragma unroll
      for (int ks = 0; ks < 4; ++ks) {
        bf16x8 vf = lds_frag(Vs[cur] + (32 * jb + l31) * LDK + ks * 16 + hi * 8);
        o[jb] = MFMA32(vf, pa[ks], o[jb]);
      }

    // (g) write staged regs into the OTHER buffer; one barrier publishes it
    if (t + 1 < NTILE) {
      lds_st16(Ks[cur ^ 1] + srow * LDK + scol, kr0);
      lds_st16(Ks[cur ^ 1] + srow * LDK + scol + 8, kr1);
      lds_st16(Vs[cur ^ 1] + srow * LDK + scol, vr0);
      lds_st16(Vs[cur ^ 1] + srow * LDK + scol + 8, vr1);
    }
    __syncthreads();
    cur ^= 1;
  }

  // epilogue: normalize, write ctx[token, h*64+d]
  {
    float inv = 1.0f / lq;
    const int tok = q0 + w * 32 + l31;
    size_t base = ((size_t)b * L_SEQ + tok) * DM + h * DK;
#pragma unroll
    for (int jb = 0; jb < 2; ++jb)
#pragma unroll
      for (int c = 0; c < 4; ++c) {
        ushort4 pk;   // regs 4c..4c+3 -> d = 32jb + 8c + 4hi + 0..3
        pk.x = f2bf(o[jb][4 * c + 0] * inv);
        pk.y = f2bf(o[jb][4 * c + 1] * inv);
        pk.z = f2bf(o[jb][4 * c + 2] * inv);
        pk.w = f2bf(o[jb][4 * c + 3] * inv);
        *(ushort4*)&ctx[base + jb * 32 + c * 8 + hi * 4] = pk;
      }
  }
}

// ---------------- launch ----------------
extern "C" void kernel_launch(void* const* d_in, const int* in_sizes, int n_in,
                              void* d_out, int out_size, void* d_ws, size_t ws_size,
                              hipStream_t stream) {
  (void)in_sizes; (void)n_in; (void)out_size; (void)ws_size;
  const float* x  = (const float*)d_in[0];
  const float* Wq = (const float*)d_in[1];
  const float* bq = (const float*)d_in[2];
  const float* Wk = (const float*)d_in[3];
  const float* bk = (const float*)d_in[4];
  const float* Wv = (const float*)d_in[5];
  const float* bv = (const float*)d_in[6];
  const float* Wo = (const float*)d_in[7];
  const float* bo = (const float*)d_in[8];

  char* ws = (char*)d_ws;
  unsigned short* xb  = (unsigned short*)(ws);                    // 16 MB
  unsigned short* wqb = (unsigned short*)(ws + (16ull << 20));    // 4 x 2 MB contiguous
  unsigned short* wkb = (unsigned short*)(ws + (18ull << 20));
  unsigned short* wvb = (unsigned short*)(ws + (20ull << 20));
  unsigned short* wob = (unsigned short*)(ws + (22ull << 20));
  unsigned short* Qb  = (unsigned short*)(ws + (24ull << 20));
  unsigned short* Kb  = (unsigned short*)(ws + (40ull << 20));
  unsigned short* VTb = (unsigned short*)(ws + (56ull << 20));
  unsigned short* ctx = xb;

  cvt_f32_bf16<<<2048, 256, 0, stream>>>(x, xb, M_TOK * DM / 4);
  cvt_w4<<<4096, 256, 0, stream>>>(Wq, Wk, Wv, Wo, wqb);

  dim3 gg(DM / BN, M_TOK / BM);
  // Q pre-scaled by 0.125 * log2(e): softmax runs in exp2 domain
  gemm_bt<0><<<gg, 256, 0, stream>>>(xb, wqb, bq, 0.1803368801f, Qb, M_TOK, DM, DM);
  gemm_bt<0><<<gg, 256, 0, stream>>>(xb, wkb, bk, 1.0f, Kb, M_TOK, DM, DM);
  gemm_bt<1><<<gg, 256, 0, stream>>>(xb, wvb, bv, 1.0f, VTb, M_TOK, DM, DM);

  dim3 ga(BATCH * NH, L_SEQ / 128);
  flash_attn<<<ga, 256, 0, stream>>>(Qb, Kb, VTb, ctx);

  gemm_bt<2><<<gg, 256, 0, stream>>>(ctx, wob, bo, 1.0f, d_out, M_TOK, DM, DM);
}

// Round 7
// 239.385 us; speedup vs baseline: 1.0923x; 1.0923x over previous
//
#include <hip/hip_runtime.h>
#include <stdint.h>

#define L_SEQ   2048
#define DM      1024
#define NH      16
#define DK      64
#define BATCH   4
#define M_TOK   (BATCH * L_SEQ)   // 8192

typedef __attribute__((ext_vector_type(8))) short bf16x8;
typedef __attribute__((ext_vector_type(4))) float f32x4;
typedef __attribute__((ext_vector_type(16))) float f32x16;
typedef __attribute__((ext_vector_type(4))) unsigned int u32x4;

typedef __attribute__((address_space(1))) void void_g;
typedef __attribute__((address_space(3))) void void_l;

#define EXP2F(x) __builtin_amdgcn_exp2f(x)

__device__ __forceinline__ unsigned short f2bf(float f) {
  unsigned int u = __builtin_bit_cast(unsigned int, f);
  u += 0x7FFFu + ((u >> 16) & 1u);
  return (unsigned short)(u >> 16);
}

// ---------------- fp32 -> bf16 converts ----------------
__global__ void cvt_f32_bf16(const float* __restrict__ src,
                             unsigned short* __restrict__ dst, int n4) {
  int i = blockIdx.x * blockDim.x + threadIdx.x;
  int stride = gridDim.x * blockDim.x;
  for (; i < n4; i += stride) {
    float4 v = ((const float4*)src)[i];
    ushort4 o;
    o.x = f2bf(v.x); o.y = f2bf(v.y); o.z = f2bf(v.z); o.w = f2bf(v.w);
    ((ushort4*)dst)[i] = o;
  }
}

// 4 weight matrices (1024x1024 each) -> contiguous bf16 dst, one launch
__global__ void cvt_w4(const float* __restrict__ s0, const float* __restrict__ s1,
                       const float* __restrict__ s2, const float* __restrict__ s3,
                       unsigned short* __restrict__ dst) {
  int i = blockIdx.x * blockDim.x + threadIdx.x;      // 0 .. 4*262144-1
  int sel = i >> 18, j = i & 0x3FFFF;
  const float* s = sel == 0 ? s0 : sel == 1 ? s1 : sel == 2 ? s2 : s3;
  float4 v = ((const float4*)s)[j];
  ushort4 o;
  o.x = f2bf(v.x); o.y = f2bf(v.y); o.z = f2bf(v.z); o.w = f2bf(v.w);
  ((ushort4*)(dst + (size_t)sel * DM * DM))[j] = o;
}

// ---------------- GEMM tile core (m97 structure, 128x128, BK=32) ----------
#define BM 128
#define BN 128
#define BKK 32

// staging + MFMA main loop shared by both GEMM kernels (acc in-place)
__device__ __forceinline__ void gemm_core(
    const unsigned short* __restrict__ A, const unsigned short* __restrict__ Bw,
    unsigned short* As, unsigned short* Bs,
    int tm, int tn, int K, int wm, int wn, int lane, int wid,
    f32x4 (&acc)[4][4]) {
  const int lr = lane & 15;
  const int lk = (lane >> 4) * 8;
  for (int k0 = 0; k0 < K; k0 += BKK) {
#pragma unroll
    for (int j = 0; j < 2; ++j) {
      int e0 = (wid * 2 + j) * 512;
      int e = e0 + lane * 8;
      int r = e >> 5, c = e & 31;
      __builtin_amdgcn_global_load_lds(
          (const void_g*)(A + (size_t)(tm + r) * K + k0 + c),
          (void_l*)(As + e0), 16, 0, 0);
      __builtin_amdgcn_global_load_lds(
          (const void_g*)(Bw + (size_t)(tn + r) * K + k0 + c),
          (void_l*)(Bs + e0), 16, 0, 0);
    }
    __syncthreads();

    bf16x8 a[4], b[4];
#pragma unroll
    for (int m = 0; m < 4; ++m)
      a[m] = *(const bf16x8*)&As[(wm * 64 + m * 16 + lr) * BKK + lk];
#pragma unroll
    for (int n = 0; n < 4; ++n)
      b[n] = *(const bf16x8*)&Bs[(wn * 64 + n * 16 + lr) * BKK + lk];
#pragma unroll
    for (int m = 0; m < 4; ++m)
#pragma unroll
      for (int n = 0; n < 4; ++n)
        acc[m][n] = __builtin_amdgcn_mfma_f32_16x16x32_bf16(a[m], b[n], acc[m][n], 0, 0, 0);
    __syncthreads();
  }
}

// Fused QKV projection: A[8192,1024] @ (wq|wk|wv)[3072,1024]^T.
// Output segment sel=0 -> Q [B,H,L,DK] bf16 (scaled), sel=1 -> K same,
// sel=2 -> V transposed [B,H,DK,L]. outQ/K/V spaced 8M elems (16MB) apart.
__global__ __launch_bounds__(256) void gemm_qkv(
    const unsigned short* __restrict__ A,
    const unsigned short* __restrict__ Bw,
    const float* __restrict__ bq, const float* __restrict__ bk,
    const float* __restrict__ bv, float qscale,
    unsigned short* __restrict__ outQ) {
  __shared__ unsigned short As[BM * BKK];
  __shared__ unsigned short Bs[BN * BKK];
  const int tidx = threadIdx.x;
  const int wid = tidx >> 6, lane = tidx & 63;
  const int wm = wid >> 1, wn = wid & 1;
  const int tm = blockIdx.y * BM, tn = blockIdx.x * BN;

  f32x4 acc[4][4];
#pragma unroll
  for (int m = 0; m < 4; ++m)
#pragma unroll
    for (int n = 0; n < 4; ++n) acc[m][n] = (f32x4)0.0f;

  gemm_core(A, Bw, As, Bs, tm, tn, DM, wm, wn, lane, wid, acc);

  const int sel = tn >> 10;                 // block-uniform segment
  const float* bias = sel == 0 ? bq : sel == 1 ? bk : bv;
  const float scl = sel == 0 ? qscale : 1.0f;
  unsigned short* dst = outQ + (size_t)sel * (8u << 20);

#pragma unroll
  for (int m = 0; m < 4; ++m) {
    int row0 = tm + wm * 64 + m * 16 + (lane >> 4) * 4;
#pragma unroll
    for (int n = 0; n < 4; ++n) {
      int col = tn + wn * 64 + n * 16 + (lane & 15);
      int c10 = col & 1023;
      int h = c10 >> 6, dd = c10 & 63;
      float bc = bias[c10];
#pragma unroll
      for (int jj = 0; jj < 4; ++jj) {
        float v = (acc[m][n][jj] + bc) * scl;
        int R = row0 + jj;
        int bb = R >> 11, ll = R & (L_SEQ - 1);
        if (sel < 2)
          dst[(((size_t)bb * NH + h) * L_SEQ + ll) * DK + dd] = f2bf(v);
        else
          dst[(((size_t)bb * NH + h) * DK + dd) * L_SEQ + ll] = f2bf(v);
      }
    }
  }
}

// Output projection: C = A @ Wo^T + bo, fp32 out [M, DM]
__global__ __launch_bounds__(256) void gemm_out(
    const unsigned short* __restrict__ A,
    const unsigned short* __restrict__ Bw,
    const float* __restrict__ bias,
    float* __restrict__ out) {
  __shared__ unsigned short As[BM * BKK];
  __shared__ unsigned short Bs[BN * BKK];
  const int tidx = threadIdx.x;
  const int wid = tidx >> 6, lane = tidx & 63;
  const int wm = wid >> 1, wn = wid & 1;
  const int tm = blockIdx.y * BM, tn = blockIdx.x * BN;

  f32x4 acc[4][4];
#pragma unroll
  for (int m = 0; m < 4; ++m)
#pragma unroll
    for (int n = 0; n < 4; ++n) acc[m][n] = (f32x4)0.0f;

  gemm_core(A, Bw, As, Bs, tm, tn, DM, wm, wn, lane, wid, acc);

#pragma unroll
  for (int m = 0; m < 4; ++m) {
    int row0 = tm + wm * 64 + m * 16 + (lane >> 4) * 4;
#pragma unroll
    for (int n = 0; n < 4; ++n) {
      int col = tn + wn * 64 + n * 16 + (lane & 15);
      float bc = bias[col];
#pragma unroll
      for (int jj = 0; jj < 4; ++jj)
        out[(size_t)(row0 + jj) * DM + col] = acc[m][n][jj] + bc;
    }
  }
}

// ---------------- flash attention: swapped 32x32, 32 q/wave ----------------
// Q,K: [B,H,L,DK] bf16 (Q pre-scaled by 0.125*log2e). VT: [B,H,DK,L] bf16.
#define KVB 64
#define LDK 68                 // 34-dword rows -> <=2-way banks (free)
#define NTILE (L_SEQ / KVB)
#define CLIP2 144.269504f      // 100*log2(e)
#define THR2  11.5415f         // 8*log2(e)

__device__ __forceinline__ bf16x8 lds_frag(const unsigned short* p) {
  uint2 a = *(const uint2*)p;
  uint2 b = *(const uint2*)(p + 4);
  u32x4 t = {a.x, a.y, b.x, b.y};
  return __builtin_bit_cast(bf16x8, t);
}

__device__ __forceinline__ void lds_st16(unsigned short* p, uint4 v) {
  *(uint2*)p = make_uint2(v.x, v.y);
  *(uint2*)(p + 4) = make_uint2(v.z, v.w);
}

// D.lo16 = bf16(a), D.hi16 = bf16(b)
__device__ __forceinline__ unsigned cvtpk(float a, float b) {
  unsigned r;
  asm("v_cvt_pk_bf16_f32 %0, %1, %2" : "=v"(r) : "v"(a), "v"(b));
  return r;
}

// a' = {a.lo32lanes, b.lo32lanes}; b' = {a.hi32lanes, b.hi32lanes}
// Round-3-VERIFIED shfl implementation.
__device__ __forceinline__ void pl32swap(unsigned& a, unsigned& b) {
  unsigned sa = (unsigned)__shfl_xor((int)a, 32);
  unsigned sb = (unsigned)__shfl_xor((int)b, 32);
  int hi = (threadIdx.x & 63) >> 5;
  unsigned na = hi ? sb : a;
  unsigned nb = hi ? b : sa;
  a = na; b = nb;
}

// every lane gets (x[lane&31], x[(lane&31)+32])
__device__ __forceinline__ void xpair32(float x, float& lo, float& hi2) {
  unsigned a = __builtin_bit_cast(unsigned, x), b = a;
  pl32swap(a, b);
  lo = __builtin_bit_cast(float, a);
  hi2 = __builtin_bit_cast(float, b);
}

#define MFMA32(a, b, c) __builtin_amdgcn_mfma_f32_32x32x16_bf16(a, b, c, 0, 0, 0)

__global__ __launch_bounds__(256, 4) void flash_attn(
    const unsigned short* __restrict__ Qg,
    const unsigned short* __restrict__ Kg,
    const unsigned short* __restrict__ VTg,
    unsigned short* __restrict__ ctx) {
  __shared__ unsigned short Ks[2][64 * LDK];
  __shared__ unsigned short Vs[2][64 * LDK];

  const int bh = blockIdx.x, b = bh >> 4, h = bh & 15;
  const int q0 = blockIdx.y * 128;
  const int tid = threadIdx.x;
  const int w = tid >> 6, lane = tid & 63;
  const int l31 = lane & 31, hi = lane >> 5;
  const size_t head = (size_t)bh * (L_SEQ * DK);

  const int srow = w * 16 + (lane >> 2);     // staging row (4 waves cover 64)
  const int scol = (lane & 3) * 16;

  // Q fragments (B-operand layout: col=lane&31, k=hi*8+j), 32 q rows/wave
  bf16x8 qf[4];
  {
    const unsigned short* qp = Qg + head + (size_t)(q0 + w * 32 + l31) * DK + hi * 8;
#pragma unroll
    for (int ks = 0; ks < 4; ++ks) qf[ks] = *(const bf16x8*)(qp + ks * 16);
  }

  f32x16 o[2];
  o[0] = (f32x16)0.0f; o[1] = (f32x16)0.0f;
  float mq = -1e30f, lq = 0.0f;

  { // prologue: stage tile 0 into buffer 0
    const unsigned short* kp = Kg + head + (size_t)srow * DK + scol;
    uint4 k0 = *(const uint4*)kp, k1 = *(const uint4*)(kp + 8);
    const unsigned short* vp = VTg + head + (size_t)srow * L_SEQ + scol;
    uint4 v0 = *(const uint4*)vp, v1 = *(const uint4*)(vp + 8);
    lds_st16(Ks[0] + srow * LDK + scol, k0);
    lds_st16(Ks[0] + srow * LDK + scol + 8, k1);
    lds_st16(Vs[0] + srow * LDK + scol, v0);
    lds_st16(Vs[0] + srow * LDK + scol + 8, v1);
  }
  __syncthreads();

  int cur = 0;
  for (int t = 0; t < NTILE; ++t) {
    uint4 kr0, kr1, vr0, vr1;
    const int kv0n = (t + 1) * KVB;
    // (a) issue next K loads early (HBM/L2 latency hides under QK+softmax)
    if (t + 1 < NTILE) {
      const unsigned short* kp = Kg + head + (size_t)(kv0n + srow) * DK + scol;
      kr0 = *(const uint4*)kp; kr1 = *(const uint4*)(kp + 8);
    }

    // (b) QK^T: S[kv][q], lane's q = l31
    f32x16 s0 = (f32x16)0.0f, s1 = (f32x16)0.0f;
#pragma unroll
    for (int ks = 0; ks < 4; ++ks) {
      bf16x8 k0 = lds_frag(Ks[cur] + l31 * LDK + ks * 16 + hi * 8);
      s0 = MFMA32(k0, qf[ks], s0);
      bf16x8 k1 = lds_frag(Ks[cur] + (32 + l31) * LDK + ks * 16 + hi * 8);
      s1 = MFMA32(k1, qf[ks], s1);
    }

    // (c) clip + tile max: med3 clamp, TREE reduce (depth 5, was serial 16)
    float tm[16];
#pragma unroll
    for (int r = 0; r < 16; ++r) {
      s0[r] = __builtin_amdgcn_fmed3f(s0[r], -CLIP2, CLIP2);
      s1[r] = __builtin_amdgcn_fmed3f(s1[r], -CLIP2, CLIP2);
      tm[r] = fmaxf(s0[r], s1[r]);
    }
#pragma unroll
    for (int st = 8; st >= 1; st >>= 1)
#pragma unroll
      for (int r = 0; r < st; ++r) tm[r] = fmaxf(tm[r], tm[r + st]);
    float tmax;
    {
      float a, c; xpair32(tm[0], a, c);
      tmax = fmaxf(a, c);
    }
    // defer-max (T13)
    if (!__all(tmax - mq <= THR2)) {
      float mn = fmaxf(mq, tmax);
      float corr = EXP2F(mq - mn);
      lq *= corr;
#pragma unroll
      for (int r = 0; r < 16; ++r) { o[0][r] *= corr; o[1][r] *= corr; }
      mq = mn;
    }
#pragma unroll
    for (int r = 0; r < 16; ++r) {
      s0[r] = EXP2F(s0[r] - mq);
      s1[r] = EXP2F(s1[r] - mq);
    }
    // ls TREE sum (depth ~5, was serial 32)
    float l4[4];
#pragma unroll
    for (int r = 0; r < 4; ++r)
      l4[r] = ((s0[r] + s0[r + 4]) + (s0[r + 8] + s0[r + 12]))
            + ((s1[r] + s1[r + 4]) + (s1[r + 8] + s1[r + 12]));
    float ls = (l4[0] + l4[1]) + (l4[2] + l4[3]);
    {
      float a, c; xpair32(ls, a, c);
      lq += a + c;
    }

    // (d) pack P into PV B-frags: frag[ks] elem j <- P[kv=16ks+8hi+j][q]
    bf16x8 pa[4];
#pragma unroll
    for (int ks = 0; ks < 4; ++ks) {
      const int s8 = (ks & 1) * 8;
      const f32x16 sv = (ks < 2) ? s0 : s1;
      unsigned uA0 = cvtpk(sv[s8 + 0], sv[s8 + 1]);
      unsigned uA1 = cvtpk(sv[s8 + 2], sv[s8 + 3]);
      unsigned uB0 = cvtpk(sv[s8 + 4], sv[s8 + 5]);
      unsigned uB1 = cvtpk(sv[s8 + 6], sv[s8 + 7]);
      pl32swap(uA0, uB0);
      pl32swap(uA1, uB1);
      u32x4 tt = {uA0, uA1, uB0, uB1};
      pa[ks] = __builtin_bit_cast(bf16x8, tt);
    }

    // (e) issue next V loads (hides under PV MFMAs)
    if (t + 1 < NTILE) {
      const unsigned short* vp = VTg + head + (size_t)srow * L_SEQ + kv0n + scol;
      vr0 = *(const uint4*)vp; vr1 = *(const uint4*)(vp + 8);
    }

    // (f) PV: O^T[d][q] += VT[d][kv] * P^T[q][kv]
#pragma unroll
    for (int jb = 0; jb < 2; ++jb)
#pragma unroll
      for (int ks = 0; ks < 4; ++ks) {
        bf16x8 vf = lds_frag(Vs[cur] + (32 * jb + l31) * LDK + ks * 16 + hi * 8);
        o[jb] = MFMA32(vf, pa[ks], o[jb]);
      }

    // (g) write staged regs into the OTHER buffer; one barrier publishes it
    if (t + 1 < NTILE) {
      lds_st16(Ks[cur ^ 1] + srow * LDK + scol, kr0);
      lds_st16(Ks[cur ^ 1] + srow * LDK + scol + 8, kr1);
      lds_st16(Vs[cur ^ 1] + srow * LDK + scol, vr0);
      lds_st16(Vs[cur ^ 1] + srow * LDK + scol + 8, vr1);
    }
    __syncthreads();
    cur ^= 1;
  }

  // epilogue: normalize, write ctx[token, h*64+d]
  {
    float inv = 1.0f / lq;
    const int tok = q0 + w * 32 + l31;
    size_t base = ((size_t)b * L_SEQ + tok) * DM + h * DK;
#pragma unroll
    for (int jb = 0; jb < 2; ++jb)
#pragma unroll
      for (int c = 0; c < 4; ++c) {
        ushort4 pk;   // regs 4c..4c+3 -> d = 32jb + 8c + 4hi + 0..3
        pk.x = f2bf(o[jb][4 * c + 0] * inv);
        pk.y = f2bf(o[jb][4 * c + 1] * inv);
        pk.z = f2bf(o[jb][4 * c + 2] * inv);
        pk.w = f2bf(o[jb][4 * c + 3] * inv);
        *(ushort4*)&ctx[base + jb * 32 + c * 8 + hi * 4] = pk;
      }
  }
}

// ---------------- launch ----------------
extern "C" void kernel_launch(void* const* d_in, const int* in_sizes, int n_in,
                              void* d_out, int out_size, void* d_ws, size_t ws_size,
                              hipStream_t stream) {
  (void)in_sizes; (void)n_in; (void)out_size; (void)ws_size;
  const float* x  = (const float*)d_in[0];
  const float* Wq = (const float*)d_in[1];
  const float* bq = (const float*)d_in[2];
  const float* Wk = (const float*)d_in[3];
  const float* bk = (const float*)d_in[4];
  const float* Wv = (const float*)d_in[5];
  const float* bv = (const float*)d_in[6];
  const float* Wo = (const float*)d_in[7];
  const float* bo = (const float*)d_in[8];

  char* ws = (char*)d_ws;
  unsigned short* xb  = (unsigned short*)(ws);                    // 16 MB
  unsigned short* wqb = (unsigned short*)(ws + (16ull << 20));    // wq|wk|wv|wo contiguous
  unsigned short* wob = (unsigned short*)(ws + (22ull << 20));
  unsigned short* Qb  = (unsigned short*)(ws + (24ull << 20));    // Q|K|VT, 16MB apart
  unsigned short* Kb  = (unsigned short*)(ws + (40ull << 20));
  unsigned short* VTb = (unsigned short*)(ws + (56ull << 20));
  unsigned short* ctx = xb;

  cvt_f32_bf16<<<2048, 256, 0, stream>>>(x, xb, M_TOK * DM / 4);
  cvt_w4<<<4096, 256, 0, stream>>>(Wq, Wk, Wv, Wo, wqb);

  // Fused QKV projection; Q scaled by 0.125*log2(e) (exp2-domain softmax)
  gemm_qkv<<<dim3(3 * DM / BN, M_TOK / BM), 256, 0, stream>>>(
      xb, wqb, bq, bk, bv, 0.1803368801f, Qb);

  dim3 ga(BATCH * NH, L_SEQ / 128);
  flash_attn<<<ga, 256, 0, stream>>>(Qb, Kb, VTb, ctx);

  gemm_out<<<dim3(DM / BN, M_TOK / BM), 256, 0, stream>>>(ctx, wob, bo, (float*)d_out);
}

// Round 8
// 237.213 us; speedup vs baseline: 1.1023x; 1.0092x over previous
//
#include <hip/hip_runtime.h>
#include <stdint.h>

#define L_SEQ   2048
#define DM      1024
#define NH      16
#define DK      64
#define BATCH   4
#define M_TOK   (BATCH * L_SEQ)   // 8192

typedef __attribute__((ext_vector_type(8))) short bf16x8;
typedef __attribute__((ext_vector_type(4))) float f32x4;
typedef __attribute__((ext_vector_type(16))) float f32x16;
typedef __attribute__((ext_vector_type(4))) unsigned int u32x4;

typedef __attribute__((address_space(1))) void void_g;
typedef __attribute__((address_space(3))) void void_l;

#define EXP2F(x) __builtin_amdgcn_exp2f(x)

__device__ __forceinline__ unsigned short f2bf(float f) {
  unsigned int u = __builtin_bit_cast(unsigned int, f);
  u += 0x7FFFu + ((u >> 16) & 1u);
  return (unsigned short)(u >> 16);
}

// ---------------- fp32 -> bf16 converts ----------------
__global__ void cvt_f32_bf16(const float* __restrict__ src,
                             unsigned short* __restrict__ dst, int n4) {
  int i = blockIdx.x * blockDim.x + threadIdx.x;
  int stride = gridDim.x * blockDim.x;
  for (; i < n4; i += stride) {
    float4 v = ((const float4*)src)[i];
    ushort4 o;
    o.x = f2bf(v.x); o.y = f2bf(v.y); o.z = f2bf(v.z); o.w = f2bf(v.w);
    ((ushort4*)dst)[i] = o;
  }
}

// 4 weight matrices (1024x1024 each) -> contiguous bf16 dst, one launch
__global__ void cvt_w4(const float* __restrict__ s0, const float* __restrict__ s1,
                       const float* __restrict__ s2, const float* __restrict__ s3,
                       unsigned short* __restrict__ dst) {
  int i = blockIdx.x * blockDim.x + threadIdx.x;      // 0 .. 4*262144-1
  int sel = i >> 18, j = i & 0x3FFFF;
  const float* s = sel == 0 ? s0 : sel == 1 ? s1 : sel == 2 ? s2 : s3;
  float4 v = ((const float4*)s)[j];
  ushort4 o;
  o.x = f2bf(v.x); o.y = f2bf(v.y); o.z = f2bf(v.z); o.w = f2bf(v.w);
  ((ushort4*)(dst + (size_t)sel * DM * DM))[j] = o;
}

// ---------------- deep-pipelined GEMM (T2+T3+T4+T5) ----------------
// C = A[8192,1024] @ Bw[N,1024]^T (+bias, per-EPI epilogue)
// BM=128 BN=256 BK=64, 512 thr (8 waves 2Mx4N, 64x64/wave), 3-buf depth-2.
// LDS tile rows are 128B = 8 x 16B units; swizzle unit' = unit ^ (row&7).
// global_load_lds writes linearly, so the GLOBAL source is pre-swizzled
// with src_unit = (l&7)^(l>>3) (same involution; verified bijective).
#define GBM 128
#define GBN 256
#define GBK 64
#define NKT (DM / GBK)            // 16 K-tiles
#define ATILE (GBM * GBK)         // 8192 elems
#define BTILE (GBN * GBK)         // 16384 elems
#define BUFE (ATILE + BTILE)      // 24576 elems per buffer

__device__ __forceinline__ void stage_tile(
    const unsigned short* __restrict__ A, const unsigned short* __restrict__ Bw,
    unsigned short* buf, int tm, int tn, int k0, int t) {
  const int l = t & 63, w = t >> 6;
  const int su = (l & 7) ^ (l >> 3);          // pre-swizzled source unit
  const int rw = w * 8 + (l >> 3);            // row within a 64-row round
  const unsigned short* asrc = A + (size_t)(tm + rw) * DM + k0 + su * 8;
  const unsigned short* bsrc = Bw + (size_t)(tn + rw) * DM + k0 + su * 8;
#pragma unroll
  for (int r = 0; r < 2; ++r)                 // A: 128 rows = 2 rounds
    __builtin_amdgcn_global_load_lds(
        (const void_g*)(asrc + (size_t)r * 64 * DM),
        (void_l*)(buf + r * 4096 + w * 512), 16, 0, 0);
#pragma unroll
  for (int r = 0; r < 4; ++r)                 // B: 256 rows = 4 rounds
    __builtin_amdgcn_global_load_lds(
        (const void_g*)(bsrc + (size_t)r * 64 * DM),
        (void_l*)(buf + ATILE + r * 4096 + w * 512), 16, 0, 0);
}

__device__ __forceinline__ bf16x8 frag_ld(const unsigned short* base, int R, int u) {
  return *(const bf16x8*)(base + R * 64 + (u ^ (R & 7)) * 8);
}

// EPI 0: QKV-split epilogue (bf16, head layouts). EPI 1: fp32 out + bias.
template <int EPI>
__global__ __launch_bounds__(512, 2) void gemm8(
    const unsigned short* __restrict__ A,
    const unsigned short* __restrict__ Bw,
    const float* __restrict__ b0, const float* __restrict__ b1,
    const float* __restrict__ b2, float qscale,
    void* __restrict__ out) {
  __shared__ unsigned short L[3 * BUFE];      // 147456 B

  const int tidx = threadIdx.x;
  const int wid = tidx >> 6, lane = tidx & 63;
  const int wm = wid >> 2, wn = wid & 3;      // 2M x 4N
  const int lr = lane & 15, lg4 = lane >> 4;

  // bijective XCD swizzle (nwg % 8 == 0 for both grids)
  int wg = blockIdx.y * gridDim.x + blockIdx.x;
  int nwg = gridDim.x * gridDim.y;
  int swz = (wg & 7) * (nwg >> 3) + (wg >> 3);
  const int tm = (swz / gridDim.x) * GBM, tn = (swz % gridDim.x) * GBN;

  f32x4 acc[4][4];
#pragma unroll
  for (int m = 0; m < 4; ++m)
#pragma unroll
    for (int n = 0; n < 4; ++n) acc[m][n] = (f32x4)0.0f;

  // prologue: 2 tiles in flight
  stage_tile(A, Bw, L, tm, tn, 0, tidx);
  stage_tile(A, Bw, L + BUFE, tm, tn, GBK, tidx);
  asm volatile("s_waitcnt vmcnt(6)" ::: "memory");
  __builtin_amdgcn_s_barrier();

  for (int i = 0; i < NKT; ++i) {
    unsigned short* cb = L + (i % 3) * BUFE;
    if (i + 2 < NKT)
      stage_tile(A, Bw, L + ((i + 2) % 3) * BUFE, tm, tn, (i + 2) * GBK, tidx);
#pragma unroll
    for (int ks = 0; ks < 2; ++ks) {
      bf16x8 a[4], b[4];
#pragma unroll
      for (int m = 0; m < 4; ++m)
        a[m] = frag_ld(cb, wm * 64 + m * 16 + lr, ks * 4 + lg4);
#pragma unroll
      for (int n = 0; n < 4; ++n)
        b[n] = frag_ld(cb + ATILE, wn * 64 + n * 16 + lr, ks * 4 + lg4);
      __builtin_amdgcn_s_setprio(1);
#pragma unroll
      for (int m = 0; m < 4; ++m)
#pragma unroll
        for (int n = 0; n < 4; ++n)
          acc[m][n] = __builtin_amdgcn_mfma_f32_16x16x32_bf16(a[m], b[n], acc[m][n], 0, 0, 0);
      __builtin_amdgcn_s_setprio(0);
    }
    if (i + 2 < NKT)
      asm volatile("s_waitcnt vmcnt(6)" ::: "memory");
    else
      asm volatile("s_waitcnt vmcnt(0)" ::: "memory");
    __builtin_amdgcn_s_barrier();
  }

  // epilogue
  if (EPI == 1) {
    float* o = (float*)out;
#pragma unroll
    for (int m = 0; m < 4; ++m) {
      int row0 = tm + wm * 64 + m * 16 + lg4 * 4;
#pragma unroll
      for (int n = 0; n < 4; ++n) {
        int col = tn + wn * 64 + n * 16 + lr;
        float bc = b0[col];
#pragma unroll
        for (int jj = 0; jj < 4; ++jj)
          o[(size_t)(row0 + jj) * DM + col] = acc[m][n][jj] + bc;
      }
    }
  } else {
    const int sel = tn >> 10;                 // block-uniform (1024 % 256 == 0)
    const float* bias = sel == 0 ? b0 : sel == 1 ? b1 : b2;
    const float scl = sel == 0 ? qscale : 1.0f;
    unsigned short* dst = (unsigned short*)out + (size_t)sel * (8u << 20);
#pragma unroll
    for (int m = 0; m < 4; ++m) {
      int row0 = tm + wm * 64 + m * 16 + lg4 * 4;
#pragma unroll
      for (int n = 0; n < 4; ++n) {
        int col = tn + wn * 64 + n * 16 + lr;
        int c10 = col & 1023;
        int h = c10 >> 6, dd = c10 & 63;
        float bc = bias[c10];
#pragma unroll
        for (int jj = 0; jj < 4; ++jj) {
          float v = (acc[m][n][jj] + bc) * scl;
          int R = row0 + jj;
          int bb = R >> 11, ll = R & (L_SEQ - 1);
          if (sel < 2)
            dst[(((size_t)bb * NH + h) * L_SEQ + ll) * DK + dd] = f2bf(v);
          else
            dst[(((size_t)bb * NH + h) * DK + dd) * L_SEQ + ll] = f2bf(v);
        }
      }
    }
  }
}

// ---------------- flash attention: swapped 32x32, 32 q/wave ----------------
// Q,K: [B,H,L,DK] bf16 (Q pre-scaled by 0.125*log2e). VT: [B,H,DK,L] bf16.
#define KVB 64
#define LDK 68                 // 34-dword rows -> <=2-way banks (free)
#define NTILE (L_SEQ / KVB)
#define CLIP2 144.269504f      // 100*log2(e)
#define THR2  11.5415f         // 8*log2(e)

__device__ __forceinline__ bf16x8 lds_frag(const unsigned short* p) {
  uint2 a = *(const uint2*)p;
  uint2 b = *(const uint2*)(p + 4);
  u32x4 t = {a.x, a.y, b.x, b.y};
  return __builtin_bit_cast(bf16x8, t);
}

__device__ __forceinline__ void lds_st16(unsigned short* p, uint4 v) {
  *(uint2*)p = make_uint2(v.x, v.y);
  *(uint2*)(p + 4) = make_uint2(v.z, v.w);
}

// D.lo16 = bf16(a), D.hi16 = bf16(b)
__device__ __forceinline__ unsigned cvtpk(float a, float b) {
  unsigned r;
  asm("v_cvt_pk_bf16_f32 %0, %1, %2" : "=v"(r) : "v"(a), "v"(b));
  return r;
}

// a' = {a.lo32lanes, b.lo32lanes}; b' = {a.hi32lanes, b.hi32lanes}
// Round-3-VERIFIED shfl implementation.
__device__ __forceinline__ void pl32swap(unsigned& a, unsigned& b) {
  unsigned sa = (unsigned)__shfl_xor((int)a, 32);
  unsigned sb = (unsigned)__shfl_xor((int)b, 32);
  int hi = (threadIdx.x & 63) >> 5;
  unsigned na = hi ? sb : a;
  unsigned nb = hi ? b : sa;
  a = na; b = nb;
}

// every lane gets (x[lane&31], x[(lane&31)+32])
__device__ __forceinline__ void xpair32(float x, float& lo, float& hi2) {
  unsigned a = __builtin_bit_cast(unsigned, x), b = a;
  pl32swap(a, b);
  lo = __builtin_bit_cast(float, a);
  hi2 = __builtin_bit_cast(float, b);
}

#define MFMA32(a, b, c) __builtin_amdgcn_mfma_f32_32x32x16_bf16(a, b, c, 0, 0, 0)

__global__ __launch_bounds__(256, 4) void flash_attn(
    const unsigned short* __restrict__ Qg,
    const unsigned short* __restrict__ Kg,
    const unsigned short* __restrict__ VTg,
    unsigned short* __restrict__ ctx) {
  __shared__ unsigned short Ks[2][64 * LDK];
  __shared__ unsigned short Vs[2][64 * LDK];

  const int bh = blockIdx.x, b = bh >> 4, h = bh & 15;
  const int q0 = blockIdx.y * 128;
  const int tid = threadIdx.x;
  const int w = tid >> 6, lane = tid & 63;
  const int l31 = lane & 31, hi = lane >> 5;
  const size_t head = (size_t)bh * (L_SEQ * DK);

  const int srow = w * 16 + (lane >> 2);     // staging row (4 waves cover 64)
  const int scol = (lane & 3) * 16;

  // Q fragments (B-operand layout: col=lane&31, k=hi*8+j), 32 q rows/wave
  bf16x8 qf[4];
  {
    const unsigned short* qp = Qg + head + (size_t)(q0 + w * 32 + l31) * DK + hi * 8;
#pragma unroll
    for (int ks = 0; ks < 4; ++ks) qf[ks] = *(const bf16x8*)(qp + ks * 16);
  }

  f32x16 o[2];
  o[0] = (f32x16)0.0f; o[1] = (f32x16)0.0f;
  float mq = -1e30f, lq = 0.0f;

  { // prologue: stage tile 0 into buffer 0
    const unsigned short* kp = Kg + head + (size_t)srow * DK + scol;
    uint4 k0 = *(const uint4*)kp, k1 = *(const uint4*)(kp + 8);
    const unsigned short* vp = VTg + head + (size_t)srow * L_SEQ + scol;
    uint4 v0 = *(const uint4*)vp, v1 = *(const uint4*)(vp + 8);
    lds_st16(Ks[0] + srow * LDK + scol, k0);
    lds_st16(Ks[0] + srow * LDK + scol + 8, k1);
    lds_st16(Vs[0] + srow * LDK + scol, v0);
    lds_st16(Vs[0] + srow * LDK + scol + 8, v1);
  }
  __syncthreads();

  int cur = 0;
  for (int t = 0; t < NTILE; ++t) {
    uint4 kr0, kr1, vr0, vr1;
    const int kv0n = (t + 1) * KVB;
    // (a) issue next K loads early (HBM/L2 latency hides under QK+softmax)
    if (t + 1 < NTILE) {
      const unsigned short* kp = Kg + head + (size_t)(kv0n + srow) * DK + scol;
      kr0 = *(const uint4*)kp; kr1 = *(const uint4*)(kp + 8);
    }

    // (b) QK^T: S[kv][q], lane's q = l31
    f32x16 s0 = (f32x16)0.0f, s1 = (f32x16)0.0f;
#pragma unroll
    for (int ks = 0; ks < 4; ++ks) {
      bf16x8 k0 = lds_frag(Ks[cur] + l31 * LDK + ks * 16 + hi * 8);
      s0 = MFMA32(k0, qf[ks], s0);
      bf16x8 k1 = lds_frag(Ks[cur] + (32 + l31) * LDK + ks * 16 + hi * 8);
      s1 = MFMA32(k1, qf[ks], s1);
    }

    // (c) clip + tile max: med3 clamp, TREE reduce
    float tm[16];
#pragma unroll
    for (int r = 0; r < 16; ++r) {
      s0[r] = __builtin_amdgcn_fmed3f(s0[r], -CLIP2, CLIP2);
      s1[r] = __builtin_amdgcn_fmed3f(s1[r], -CLIP2, CLIP2);
      tm[r] = fmaxf(s0[r], s1[r]);
    }
#pragma unroll
    for (int st = 8; st >= 1; st >>= 1)
#pragma unroll
      for (int r = 0; r < st; ++r) tm[r] = fmaxf(tm[r], tm[r + st]);
    float tmax;
    {
      float a, c; xpair32(tm[0], a, c);
      tmax = fmaxf(a, c);
    }
    // defer-max (T13)
    if (!__all(tmax - mq <= THR2)) {
      float mn = fmaxf(mq, tmax);
      float corr = EXP2F(mq - mn);
      lq *= corr;
#pragma unroll
      for (int r = 0; r < 16; ++r) { o[0][r] *= corr; o[1][r] *= corr; }
      mq = mn;
    }
#pragma unroll
    for (int r = 0; r < 16; ++r) {
      s0[r] = EXP2F(s0[r] - mq);
      s1[r] = EXP2F(s1[r] - mq);
    }
    // ls TREE sum
    float l4[4];
#pragma unroll
    for (int r = 0; r < 4; ++r)
      l4[r] = ((s0[r] + s0[r + 4]) + (s0[r + 8] + s0[r + 12]))
            + ((s1[r] + s1[r + 4]) + (s1[r + 8] + s1[r + 12]));
    float ls = (l4[0] + l4[1]) + (l4[2] + l4[3]);
    {
      float a, c; xpair32(ls, a, c);
      lq += a + c;
    }

    // (d) pack P into PV B-frags: frag[ks] elem j <- P[kv=16ks+8hi+j][q]
    bf16x8 pa[4];
#pragma unroll
    for (int ks = 0; ks < 4; ++ks) {
      const int s8 = (ks & 1) * 8;
      const f32x16 sv = (ks < 2) ? s0 : s1;
      unsigned uA0 = cvtpk(sv[s8 + 0], sv[s8 + 1]);
      unsigned uA1 = cvtpk(sv[s8 + 2], sv[s8 + 3]);
      unsigned uB0 = cvtpk(sv[s8 + 4], sv[s8 + 5]);
      unsigned uB1 = cvtpk(sv[s8 + 6], sv[s8 + 7]);
      pl32swap(uA0, uB0);
      pl32swap(uA1, uB1);
      u32x4 tt = {uA0, uA1, uB0, uB1};
      pa[ks] = __builtin_bit_cast(bf16x8, tt);
    }

    // (e) issue next V loads (hides under PV MFMAs)
    if (t + 1 < NTILE) {
      const unsigned short* vp = VTg + head + (size_t)srow * L_SEQ + kv0n + scol;
      vr0 = *(const uint4*)vp; vr1 = *(const uint4*)(vp + 8);
    }

    // (f) PV: O^T[d][q] += VT[d][kv] * P^T[q][kv]
#pragma unroll
    for (int jb = 0; jb < 2; ++jb)
#pragma unroll
      for (int ks = 0; ks < 4; ++ks) {
        bf16x8 vf = lds_frag(Vs[cur] + (32 * jb + l31) * LDK + ks * 16 + hi * 8);
        o[jb] = MFMA32(vf, pa[ks], o[jb]);
      }

    // (g) write staged regs into the OTHER buffer; one barrier publishes it
    if (t + 1 < NTILE) {
      lds_st16(Ks[cur ^ 1] + srow * LDK + scol, kr0);
      lds_st16(Ks[cur ^ 1] + srow * LDK + scol + 8, kr1);
      lds_st16(Vs[cur ^ 1] + srow * LDK + scol, vr0);
      lds_st16(Vs[cur ^ 1] + srow * LDK + scol + 8, vr1);
    }
    __syncthreads();
    cur ^= 1;
  }

  // epilogue: normalize, write ctx[token, h*64+d]
  {
    float inv = 1.0f / lq;
    const int tok = q0 + w * 32 + l31;
    size_t base = ((size_t)b * L_SEQ + tok) * DM + h * DK;
#pragma unroll
    for (int jb = 0; jb < 2; ++jb)
#pragma unroll
      for (int c = 0; c < 4; ++c) {
        ushort4 pk;   // regs 4c..4c+3 -> d = 32jb + 8c + 4hi + 0..3
        pk.x = f2bf(o[jb][4 * c + 0] * inv);
        pk.y = f2bf(o[jb][4 * c + 1] * inv);
        pk.z = f2bf(o[jb][4 * c + 2] * inv);
        pk.w = f2bf(o[jb][4 * c + 3] * inv);
        *(ushort4*)&ctx[base + jb * 32 + c * 8 + hi * 4] = pk;
      }
  }
}

// ---------------- launch ----------------
extern "C" void kernel_launch(void* const* d_in, const int* in_sizes, int n_in,
                              void* d_out, int out_size, void* d_ws, size_t ws_size,
                              hipStream_t stream) {
  (void)in_sizes; (void)n_in; (void)out_size; (void)ws_size;
  const float* x  = (const float*)d_in[0];
  const float* Wq = (const float*)d_in[1];
  const float* bq = (const float*)d_in[2];
  const float* Wk = (const float*)d_in[3];
  const float* bk = (const float*)d_in[4];
  const float* Wv = (const float*)d_in[5];
  const float* bv = (const float*)d_in[6];
  const float* Wo = (const float*)d_in[7];
  const float* bo = (const float*)d_in[8];

  char* ws = (char*)d_ws;
  unsigned short* xb  = (unsigned short*)(ws);                    // 16 MB
  unsigned short* wqb = (unsigned short*)(ws + (16ull << 20));    // wq|wk|wv|wo contiguous
  unsigned short* wob = (unsigned short*)(ws + (22ull << 20));
  unsigned short* Qb  = (unsigned short*)(ws + (24ull << 20));    // Q|K|VT, 16MB apart
  unsigned short* Kb  = (unsigned short*)(ws + (40ull << 20));
  unsigned short* VTb = (unsigned short*)(ws + (56ull << 20));
  unsigned short* ctx = xb;

  cvt_f32_bf16<<<2048, 256, 0, stream>>>(x, xb, M_TOK * DM / 4);
  cvt_w4<<<4096, 256, 0, stream>>>(Wq, Wk, Wv, Wo, wqb);

  // Fused QKV projection (deep-pipelined); Q scaled by 0.125*log2(e)
  gemm8<0><<<dim3(3 * DM / GBN, M_TOK / GBM), 512, 0, stream>>>(
      xb, wqb, bq, bk, bv, 0.1803368801f, Qb);

  dim3 ga(BATCH * NH, L_SEQ / 128);
  flash_attn<<<ga, 256, 0, stream>>>(Qb, Kb, VTb, ctx);

  gemm8<1><<<dim3(DM / GBN, M_TOK / GBM), 512, 0, stream>>>(
      ctx, wob, bo, nullptr, nullptr, 1.0f, d_out);
}